// Round 8
// baseline (118.605 us; speedup 1.0000x reference)
//
#include <hip/hip_runtime.h>
#include <math.h>

#define NMAX 3008
#define NCHK 47       // ceil(3008/64) chunks of 64
#define CAPC 128      // member compaction capacity
#define NCLS 80
#define IC   12       // i-chunks for rank (12*256 >= 3000)
#define JC   16       // j-chunks for rank
#define JCH  192      // >= ceil(3000/16)=188
#define RB   (IC*JC)  // 192 rank blocks

// ---- workspace layout (bytes) ----
#define WS_DONE   0                         // u32 done counter
#define WS_FSCORE 16                        // float[NMAX] frozen score by box
#define WS_RANKC  (WS_FSCORE + 4*NMAX)      // u64[NMAX]: gt | eqlt<<16 | eq<<32

// full-wave (64) max via DPP (VALU latency, ~8 cyc/stage); uniform result.
__device__ __forceinline__ float wave_max64(float x) {
    int v;
    v = __float_as_int(x);
    x = fmaxf(x, __int_as_float(__builtin_amdgcn_update_dpp(v, v, 0x111, 0xf, 0xf, false)));
    v = __float_as_int(x);
    x = fmaxf(x, __int_as_float(__builtin_amdgcn_update_dpp(v, v, 0x112, 0xf, 0xf, false)));
    v = __float_as_int(x);
    x = fmaxf(x, __int_as_float(__builtin_amdgcn_update_dpp(v, v, 0x114, 0xf, 0xf, false)));
    v = __float_as_int(x);
    x = fmaxf(x, __int_as_float(__builtin_amdgcn_update_dpp(v, v, 0x118, 0xf, 0xf, false)));
    v = __float_as_int(x);
    x = fmaxf(x, __int_as_float(__builtin_amdgcn_update_dpp(v, v, 0x142, 0xa, 0xf, false)));
    v = __float_as_int(x);
    x = fmaxf(x, __int_as_float(__builtin_amdgcn_update_dpp(v, v, 0x143, 0xc, 0xf, false)));
    return __int_as_float(__builtin_amdgcn_readlane(__float_as_int(x), 63));
}

// ---------------- kernel 1: per-class soft-NMS (self-contained) ----------------
// Each block: (a) zero its slice of RANKC (+done), (b) scan ALL boxes for the
// global max coord (order-independent max -> bit-exact, identical per block),
// (c) compact its class, (d) exact f32 sim (validated bit-exact rounds 2-7).
__global__ void __launch_bounds__(64)
nms_class_kernel(const float* __restrict__ boxes, const float* __restrict__ scores,
                 const int* __restrict__ idxs, char* __restrict__ ws, int n) {
#pragma clang fp contract(off)
    const int c = blockIdx.x;
    const int lane = threadIdx.x;
    float* fscore = (float*)(ws + WS_FSCORE);
    unsigned long long* RANKC = (unsigned long long*)(ws + WS_RANKC);

    __shared__ float mx0[CAPC], mx1[CAPC], mx2[CAPC], mx3[CAPC], msc[CAPC];
    __shared__ unsigned short mgid[CAPC];
    __shared__ float D[64 * 64];

    // zero-init shared counters (next dispatch reads after stream ordering)
    for (int i = c * 64 + lane; i < NMAX; i += NCLS * 64) RANKC[i] = 0ull;
    if (c == 0 && lane == 0) *(unsigned*)(ws + WS_DONE) = 0u;

    // pass 1: idx staging + global coord max
    int myidx[NCHK];
    float m = -1e30f;
#pragma unroll
    for (int t = 0; t < NCHK; t++) {
        int k = t * 64 + lane;
        if (k < n) {
            myidx[t] = idxs[k];
            float4 bb = ((const float4*)boxes)[k];
            m = fmaxf(m, fmaxf(fmaxf(bb.x, bb.y), fmaxf(bb.z, bb.w)));
        } else myidx[t] = -1;
    }
    const float maxcp1 = wave_max64(m) + 1.0f;
    const float off = (float)c * maxcp1;

    // pass 2: ballot-compact members (boxes re-loads hit L1/L2)
    int base = 0;
#pragma unroll
    for (int t = 0; t < NCHK; t++) {
        bool p = (myidx[t] == c);
        unsigned long long mm = __ballot(p);
        if (p) {
            int pos = base + __popcll(mm & ((1ull << lane) - 1ull));
            if (pos < CAPC) {
                int k = t * 64 + lane;
                float4 bb = ((const float4*)boxes)[k];
                mx0[pos] = bb.x + off; mx1[pos] = bb.y + off;
                mx2[pos] = bb.z + off; mx3[pos] = bb.w + off;
                msc[pos] = scores[k];
                mgid[pos] = (unsigned short)k;
            }
        }
        base += __popcll(mm);
    }
    int cnt = base < CAPC ? base : CAPC;
    __syncthreads();

    if (cnt <= 64) {
        // fast path: one member per lane; precomputed decay matrix
        const bool v0 = lane < cnt;
        float c0 = 0, c1 = 0, c2 = 0, c3 = 0;
        if (v0) { c0 = mx0[lane]; c1 = mx1[lane]; c2 = mx2[lane]; c3 = mx3[lane]; }
        const float ab = (c2 - c0) * (c3 - c1);
        for (int i = 0; i < cnt; i++) {
            float w0 = mx0[i], w1 = mx1[i], w2 = mx2[i], w3 = mx3[i];
            float aw = (w2 - w0) * (w3 - w1);
            float x1 = fmaxf(w0, c0), y1 = fmaxf(w1, c1);
            float x2 = fminf(w2, c2), y2 = fminf(w3, c3);
            float iw = fmaxf(x2 - x1, 0.f), ih = fmaxf(y2 - y1, 0.f);
            float inter = iw * ih;
            float d = 1.0f;                     // exp(-0.0) == 1.0f exactly
            if (inter != 0.f) {
                float iou = inter / ((aw + ab) - inter);
                float arg = -(iou * iou) / 0.5f;
                d = (float)exp((double)arg);
            }
            D[i * 64 + lane] = d;
        }
        __syncthreads();

        float sc = v0 ? msc[lane] : -1.f;
        int   g  = v0 ? mgid[lane] : 0;
        float frz = 0.f;
        for (int s = 0; s < cnt; s++) {
            float M = wave_max64(sc);
            int wm = __ffsll(__ballot(sc == M)) - 1;
            float d = D[wm * 64 + lane];
            if (lane == wm) { frz = M; sc = -1.f; }
            else if (sc >= 0.f) sc = sc * d;    // same values, same order -> bit-exact
        }
        if (v0) fscore[g] = frz;
    } else {
        // fallback (cnt > 64): validated 2-slot in-loop path
        float sc0 = -1.f, sc1 = -1.f;
        float a0 = 0, a1 = 0, a2 = 0, a3 = 0, b0 = 0, b1 = 0, b2 = 0, b3 = 0;
        int g0 = 0, g1 = 0;
        if (lane < cnt) {
            sc0 = msc[lane];
            a0 = mx0[lane]; a1 = mx1[lane]; a2 = mx2[lane]; a3 = mx3[lane];
            g0 = mgid[lane];
        }
        if (64 + lane < cnt) {
            sc1 = msc[64 + lane];
            b0 = mx0[64 + lane]; b1 = mx1[64 + lane]; b2 = mx2[64 + lane]; b3 = mx3[64 + lane];
            g1 = mgid[64 + lane];
        }
        for (int s = 0; s < cnt; s++) {
            float M = fmaxf(sc0, sc1);
            for (int o = 32; o >= 1; o >>= 1) M = fmaxf(M, __shfl_xor(M, o, 64));
            unsigned long long balA = __ballot(sc0 == M);
            int wm;
            if (balA) wm = __ffsll(balA) - 1;
            else      wm = 64 + __ffsll(__ballot(sc1 == M)) - 1;
            float w0 = mx0[wm], w1 = mx1[wm], w2 = mx2[wm], w3 = mx3[wm];
            if (wm == lane)           { fscore[g0] = M; sc0 = -1.f; }
            else if (wm == 64 + lane) { fscore[g1] = M; sc1 = -1.f; }
            float area_w = (w2 - w0) * (w3 - w1);
            if (sc0 >= 0.f) {
                float x1 = fmaxf(w0, a0), y1 = fmaxf(w1, a1);
                float x2 = fminf(w2, a2), y2 = fminf(w3, a3);
                float iw = fmaxf(x2 - x1, 0.f), ih = fmaxf(y2 - y1, 0.f);
                float inter = iw * ih;
                float area_b = (a2 - a0) * (a3 - a1);
                float iou = inter / ((area_w + area_b) - inter);
                float arg = -(iou * iou) / 0.5f;
                sc0 = sc0 * (float)exp((double)arg);
            }
            if (sc1 >= 0.f) {
                float x1 = fmaxf(w0, b0), y1 = fmaxf(w1, b1);
                float x2 = fminf(w2, b2), y2 = fminf(w3, b3);
                float iw = fmaxf(x2 - x1, 0.f), ih = fmaxf(y2 - y1, 0.f);
                float inter = iw * ih;
                float area_b = (b2 - b0) * (b3 - b1);
                float iou = inter / ((area_w + area_b) - inter);
                float arg = -(iou * iou) / 0.5f;
                sc1 = sc1 * (float)exp((double)arg);
            }
        }
    }
}

// ---------------- kernel 2: fused rank + finalize (last-block pattern) ----------------
__global__ void __launch_bounds__(256)
rank_finalize_kernel(char* __restrict__ ws, float* __restrict__ out, int n) {
    const int tid = threadIdx.x;
    float* fscore = (float*)(ws + WS_FSCORE);
    unsigned long long* RANKC = (unsigned long long*)(ws + WS_RANKC);
    unsigned* done = (unsigned*)(ws + WS_DONE);

    __shared__ float sv[JCH];

    // ---- rank phase: block = (i-chunk bx, j-chunk by) ----
    const int bx = blockIdx.x % IC;
    const int by = blockIdx.x / IC;
    const int chunk = (n + JC - 1) / JC;
    const int j0 = by * chunk;
    const int jn = min(n - j0, chunk);
    for (int j = tid; j < jn; j += 256) sv[j] = fscore[j0 + j];
    __syncthreads();

    int i = bx * 256 + tid;
    if (i < n) {
        float s = fscore[i];
        int gt = 0, eq = 0, eqlt = 0;
        for (int jj = 0; jj < jn; jj++) {
            float x = sv[jj];
            gt   += (x > s) ? 1 : 0;
            eq   += (x == s) ? 1 : 0;
            eqlt += (x == s && (j0 + jj) < i) ? 1 : 0;
        }
        unsigned long long packed = (unsigned long long)(unsigned)gt
                                  | ((unsigned long long)(unsigned)eqlt << 16)
                                  | ((unsigned long long)(unsigned)eq << 32);
        atomicAdd(&RANKC[i], packed);
    }
    __syncthreads();
    __threadfence();                       // RANKC atomics visible before done++

    __shared__ int lastS;
    if (tid == 0) lastS = (atomicAdd(done, 1u) == RB - 1);
    __syncthreads();
    if (!lastS) return;

    // ---- finalize phase: only the last-done block ----
    __shared__ unsigned short ordL[NMAX];
    __shared__ float          svL[NMAX];
    __shared__ unsigned short slotL[NMAX];
    __shared__ unsigned short batL[NMAX];
    __shared__ unsigned char  tieL[NMAX];
    __shared__ int flagS, rmaxS;
    if (tid == 0) { flagS = 0; rmaxS = -1; }
    __syncthreads();

    for (int b = tid; b < n; b += 256) {
        // device-scope atomic read: coherent vs peer-XCD atomicAdds
        unsigned long long p = atomicAdd(&RANKC[b], 0ull);
        unsigned gt   = (unsigned)(p & 0xffffu);
        unsigned eqlt = (unsigned)((p >> 16) & 0xffffu);
        unsigned eq   = (unsigned)((p >> 32) & 0xffffu);
        int r = (int)(gt + eqlt);
        ordL[r] = (unsigned short)b;
        svL[r] = fscore[b];
        slotL[b] = (unsigned short)b;
        batL[b]  = (unsigned short)b;
        if (eq >= 2 && (unsigned)b < gt + eq) atomicOr(&flagS, 1);
    }
    __syncthreads();

    int rmax = -1;
    for (int r = tid; r < n; r += 256) {
        unsigned char t = (r + 1 < n) && (svL[r] == svL[r + 1]);
        tieL[r] = t;
        if (t) rmax = r;
    }
    atomicMax(&rmaxS, rmax);
    __syncthreads();

    if (flagS && tid == 0) {
        const int rstop = rmaxS + 2;
        int r = 0;
        while (r < rstop) {
            if (!tieL[r]) {
                int w = ordL[r];
                int j = slotL[w];
                int d = batL[r];
                batL[j] = (unsigned short)d;
                slotL[d] = (unsigned short)j;
                r++;
            } else {
                int g = 1;
                while (tieL[r + g - 1]) g++;
                for (int t = 0; t < g; t++) {
                    int bi = r + t;
                    int bs = slotL[ordL[bi]];
                    for (int q = r + t + 1; q < r + g; q++) {
                        int s2 = slotL[ordL[q]];
                        if (s2 < bs) { bs = s2; bi = q; }
                    }
                    unsigned short w = ordL[bi];
                    ordL[bi] = ordL[r + t];
                    ordL[r + t] = w;
                    int d = batL[r + t];
                    batL[bs] = (unsigned short)d;
                    slotL[d] = (unsigned short)bs;
                }
                r += g;
            }
        }
    }
    __syncthreads();

    for (int r = tid; r < n; r += 256) {
        float s = svL[r];
        out[r] = s;
        out[n + r] = (float)ordL[r];
        out[2 * n + r] = (s > 0.05f) ? 1.f : 0.f;
    }
}

extern "C" void kernel_launch(void* const* d_in, const int* in_sizes, int n_in,
                              void* d_out, int out_size, void* d_ws, size_t ws_size,
                              hipStream_t stream) {
    const float* boxes  = (const float*)d_in[0];  // [N,4] f32
    const float* scores = (const float*)d_in[1];  // [N]   f32
    const int*   idxs   = (const int*)d_in[2];    // [N]   i32
    float* out = (float*)d_out;                   // scores | order | keep (f32)
    char* ws = (char*)d_ws;
    const int n = in_sizes[1];

    nms_class_kernel<<<NCLS, 64, 0, stream>>>(boxes, scores, idxs, ws, n);
    rank_finalize_kernel<<<RB, 256, 0, stream>>>(ws, out, n);
}

// Round 9
// 101.770 us; speedup vs baseline: 1.1654x; 1.1654x over previous
//
#include <hip/hip_runtime.h>
#include <math.h>

#define NMAX 3008
#define CAPC 128      // member compaction capacity
#define NCLS 80
#define IC   12       // i-chunks for rank (12*256 >= 3000)
#define JC   16       // j-chunks for rank
#define JCH  192      // >= ceil(3000/16)
#define RB   (IC*JC)  // 192 rank blocks

// ---- workspace layout (bytes) ----
#define WS_DONE   0                         // u32 done counter
#define WS_FSCORE 16                        // float[NMAX] frozen score by box
#define WS_RANKC  (WS_FSCORE + 4*NMAX)      // u64[NMAX]: gt | eqlt<<16 | eq<<32

// full-wave (64) max via DPP (VALU latency); uniform result in all lanes.
__device__ __forceinline__ float wave_max64(float x) {
    int v;
    v = __float_as_int(x);
    x = fmaxf(x, __int_as_float(__builtin_amdgcn_update_dpp(v, v, 0x111, 0xf, 0xf, false)));
    v = __float_as_int(x);
    x = fmaxf(x, __int_as_float(__builtin_amdgcn_update_dpp(v, v, 0x112, 0xf, 0xf, false)));
    v = __float_as_int(x);
    x = fmaxf(x, __int_as_float(__builtin_amdgcn_update_dpp(v, v, 0x114, 0xf, 0xf, false)));
    v = __float_as_int(x);
    x = fmaxf(x, __int_as_float(__builtin_amdgcn_update_dpp(v, v, 0x118, 0xf, 0xf, false)));
    v = __float_as_int(x);
    x = fmaxf(x, __int_as_float(__builtin_amdgcn_update_dpp(v, v, 0x142, 0xa, 0xf, false)));
    v = __float_as_int(x);
    x = fmaxf(x, __int_as_float(__builtin_amdgcn_update_dpp(v, v, 0x143, 0xc, 0xf, false)));
    return __int_as_float(__builtin_amdgcn_readlane(__float_as_int(x), 63));
}

// ---------------- kernel 1: per-class soft-NMS, 4-wave parallel prep ----------------
__global__ void __launch_bounds__(256)
nms_class_kernel(const float* __restrict__ boxes, const float* __restrict__ scores,
                 const int* __restrict__ idxs, char* __restrict__ ws, int n) {
#pragma clang fp contract(off)
    const int c = blockIdx.x;
    const int tid = threadIdx.x, wid = tid >> 6, lane = tid & 63;
    float* fscore = (float*)(ws + WS_FSCORE);
    unsigned long long* RANKC = (unsigned long long*)(ws + WS_RANKC);

    __shared__ int idxS[NMAX];                 // 12 KB
    __shared__ unsigned long long maskS[NMAX / 64];
    __shared__ float mx0[CAPC], mx1[CAPC], mx2[CAPC], mx3[CAPC], msc[CAPC];
    __shared__ unsigned short mgid[CAPC];
    __shared__ float D[64 * 64];               // 16 KB
    __shared__ float redS[256];

    // zero shared counters for the next dispatch (stream-ordered)
    for (int i = c * 256 + tid; i < NMAX; i += NCLS * 256) RANKC[i] = 0ull;
    if (c == 0 && tid == 0) *(unsigned*)(ws + WS_DONE) = 0u;

    // phase 1 (all 256): stage idxs to LDS + global coord max (order-indep, exact)
    float m = -1e30f;
    for (int k = tid; k < n; k += 256) {
        idxS[k] = idxs[k];
        float4 bb = ((const float4*)boxes)[k];
        m = fmaxf(m, fmaxf(fmaxf(bb.x, bb.y), fmaxf(bb.z, bb.w)));
    }
    redS[tid] = m;
    __syncthreads();
    for (int s = 128; s > 0; s >>= 1) {
        if (tid < s) redS[tid] = fmaxf(redS[tid], redS[tid + s]);
        __syncthreads();
    }
    const float maxcp1 = redS[0] + 1.0f;
    const float off = (float)c * maxcp1;

    // phase 2a (all 4 waves): per-chunk membership masks
    const int nch = (n + 63) / 64;
    for (int t = wid; t < nch; t += 4) {
        int k = t * 64 + lane;
        bool p = (k < n) && (idxS[k] == c);
        unsigned long long mk = __ballot(p);
        if (lane == 0) maskS[t] = mk;
    }
    __syncthreads();

    // phase 2b (all 4 waves): parallel member loads; every wave walks the
    // prefix (cheap scalar popc chain), loads only its own chunks.
    int run = 0;
    for (int t = 0; t < nch; t++) {
        unsigned long long mk = maskS[t];
        if ((t & 3) == wid) {
            if ((mk >> lane) & 1ull) {
                int pos = run + __popcll(mk & ((1ull << lane) - 1ull));
                if (pos < CAPC) {
                    int k = t * 64 + lane;
                    float4 bb = ((const float4*)boxes)[k];   // L1/L2-warm
                    mx0[pos] = bb.x + off; mx1[pos] = bb.y + off;
                    mx2[pos] = bb.z + off; mx3[pos] = bb.w + off;
                    msc[pos] = scores[k];
                    mgid[pos] = (unsigned short)k;
                }
            }
        }
        run += __popcll(mk);
    }
    const int cnt = run < CAPC ? run : CAPC;   // uniform across block
    __syncthreads();

    if (cnt <= 64) {
        // phase 3 (ALL 4 waves): decay rows split across waves -> exp units
        // run concurrently on 4 SIMDs instead of one serial lane-loop.
        const bool v0 = lane < cnt;
        float c0 = 0, c1 = 0, c2 = 0, c3 = 0;
        if (v0) { c0 = mx0[lane]; c1 = mx1[lane]; c2 = mx2[lane]; c3 = mx3[lane]; }
        const float ab = (c2 - c0) * (c3 - c1);
        for (int i = wid; i < cnt; i += 4) {
            float w0 = mx0[i], w1 = mx1[i], w2 = mx2[i], w3 = mx3[i];
            float aw = (w2 - w0) * (w3 - w1);
            float x1 = fmaxf(w0, c0), y1 = fmaxf(w1, c1);
            float x2 = fminf(w2, c2), y2 = fminf(w3, c3);
            float iw = fmaxf(x2 - x1, 0.f), ih = fmaxf(y2 - y1, 0.f);
            float inter = iw * ih;
            float d = 1.0f;                     // exp(-0.0) == 1.0f exactly
            if (inter != 0.f) {
                float iou = inter / ((aw + ab) - inter);
                float arg = -(iou * iou) / 0.5f;
                d = (float)exp((double)arg);
            }
            D[i * 64 + lane] = d;
        }
        __syncthreads();

        // phase 4 (wave 0): serial selection — validated bit-exact
        if (wid == 0) {
            float sc = v0 ? msc[lane] : -1.f;
            int g = v0 ? mgid[lane] : 0;
            float frz = 0.f;
            for (int s = 0; s < cnt; s++) {
                float M = wave_max64(sc);
                int wm = __ffsll(__ballot(sc == M)) - 1;
                float d = D[wm * 64 + lane];
                if (lane == wm) { frz = M; sc = -1.f; }
                else if (sc >= 0.f) sc = sc * d;
            }
            if (v0) fscore[g] = frz;
        }
    } else if (wid == 0) {
        // fallback (cnt > 64): validated 2-slot in-loop path on wave 0
        float sc0 = -1.f, sc1 = -1.f;
        float a0 = 0, a1 = 0, a2 = 0, a3 = 0, b0 = 0, b1 = 0, b2 = 0, b3 = 0;
        int g0 = 0, g1 = 0;
        if (lane < cnt) {
            sc0 = msc[lane];
            a0 = mx0[lane]; a1 = mx1[lane]; a2 = mx2[lane]; a3 = mx3[lane];
            g0 = mgid[lane];
        }
        if (64 + lane < cnt) {
            sc1 = msc[64 + lane];
            b0 = mx0[64 + lane]; b1 = mx1[64 + lane]; b2 = mx2[64 + lane]; b3 = mx3[64 + lane];
            g1 = mgid[64 + lane];
        }
        for (int s = 0; s < cnt; s++) {
            float M = fmaxf(sc0, sc1);
            for (int o = 32; o >= 1; o >>= 1) M = fmaxf(M, __shfl_xor(M, o, 64));
            unsigned long long balA = __ballot(sc0 == M);
            int wm;
            if (balA) wm = __ffsll(balA) - 1;
            else      wm = 64 + __ffsll(__ballot(sc1 == M)) - 1;
            float w0 = mx0[wm], w1 = mx1[wm], w2 = mx2[wm], w3 = mx3[wm];
            if (wm == lane)           { fscore[g0] = M; sc0 = -1.f; }
            else if (wm == 64 + lane) { fscore[g1] = M; sc1 = -1.f; }
            float area_w = (w2 - w0) * (w3 - w1);
            if (sc0 >= 0.f) {
                float x1 = fmaxf(w0, a0), y1 = fmaxf(w1, a1);
                float x2 = fminf(w2, a2), y2 = fminf(w3, a3);
                float iw = fmaxf(x2 - x1, 0.f), ih = fmaxf(y2 - y1, 0.f);
                float inter = iw * ih;
                float area_b = (a2 - a0) * (a3 - a1);
                float iou = inter / ((area_w + area_b) - inter);
                float arg = -(iou * iou) / 0.5f;
                sc0 = sc0 * (float)exp((double)arg);
            }
            if (sc1 >= 0.f) {
                float x1 = fmaxf(w0, b0), y1 = fmaxf(w1, b1);
                float x2 = fminf(w2, b2), y2 = fminf(w3, b3);
                float iw = fmaxf(x2 - x1, 0.f), ih = fmaxf(y2 - y1, 0.f);
                float inter = iw * ih;
                float area_b = (b2 - b0) * (b3 - b1);
                float iou = inter / ((area_w + area_b) - inter);
                float arg = -(iou * iou) / 0.5f;
                sc1 = sc1 * (float)exp((double)arg);
            }
        }
    }
}

// ---------------- kernel 2: fused rank + finalize (last-block pattern) ----------------
__global__ void __launch_bounds__(256)
rank_finalize_kernel(char* __restrict__ ws, float* __restrict__ out, int n) {
    const int tid = threadIdx.x;
    float* fscore = (float*)(ws + WS_FSCORE);
    unsigned long long* RANKC = (unsigned long long*)(ws + WS_RANKC);
    unsigned* done = (unsigned*)(ws + WS_DONE);

    __shared__ float sv[JCH];

    // ---- rank phase ----
    const int bx = blockIdx.x % IC;
    const int by = blockIdx.x / IC;
    const int chunk = (n + JC - 1) / JC;
    const int j0 = by * chunk;
    const int jn = min(n - j0, chunk);
    for (int j = tid; j < jn; j += 256) sv[j] = fscore[j0 + j];
    __syncthreads();

    int i = bx * 256 + tid;
    if (i < n) {
        float s = fscore[i];
        int gt = 0, eq = 0, eqlt = 0;
        for (int jj = 0; jj < jn; jj++) {
            float x = sv[jj];
            gt   += (x > s) ? 1 : 0;
            eq   += (x == s) ? 1 : 0;
            eqlt += (x == s && (j0 + jj) < i) ? 1 : 0;
        }
        unsigned long long packed = (unsigned long long)(unsigned)gt
                                  | ((unsigned long long)(unsigned)eqlt << 16)
                                  | ((unsigned long long)(unsigned)eq << 32);
        atomicAdd(&RANKC[i], packed);
    }
    __syncthreads();
    __threadfence();

    __shared__ int lastS;
    if (tid == 0) lastS = (atomicAdd(done, 1u) == RB - 1);
    __syncthreads();
    if (!lastS) return;

    // ---- finalize phase (last block only) ----
    __shared__ unsigned short ordL[NMAX];
    __shared__ float          svL[NMAX];
    __shared__ unsigned short slotL[NMAX];
    __shared__ unsigned short batL[NMAX];
    __shared__ unsigned char  tieL[NMAX];
    __shared__ int rstopS;
    if (tid == 0) rstopS = 0;
    __syncthreads();

    for (int b = tid; b < n; b += 256) {
        unsigned long long p = atomicAdd(&RANKC[b], 0ull);   // device-coherent read
        unsigned gt   = (unsigned)(p & 0xffffu);
        unsigned eqlt = (unsigned)((p >> 16) & 0xffffu);
        unsigned eq   = (unsigned)((p >> 32) & 0xffffu);
        int r = (int)(gt + eqlt);
        ordL[r] = (unsigned short)b;
        svL[r] = fscore[b];
        slotL[b] = (unsigned short)b;
        batL[b]  = (unsigned short)b;
        // unsafe group: some member's id < group START (gt). Members with
        // id >= gt provably still sit at slot == id at group time.
        if (eq >= 2 && (unsigned)b < gt) atomicMax(&rstopS, (int)(gt + eq));
    }
    __syncthreads();

    for (int r = tid; r < n; r += 256)
        tieL[r] = (r + 1 < n) && (svL[r] == svL[r + 1]);
    __syncthreads();

    if (rstopS > 0 && tid == 0) {
        const int rstop = rstopS;
        int r = 0;
        while (r < rstop) {
            if (!tieL[r]) {
                int w = ordL[r];
                int j = slotL[w];
                int d = batL[r];
                batL[j] = (unsigned short)d;
                slotL[d] = (unsigned short)j;
                r++;
            } else {
                int g = 1;
                while (tieL[r + g - 1]) g++;
                for (int t = 0; t < g; t++) {
                    int bi = r + t;
                    int bs = slotL[ordL[bi]];
                    for (int q = r + t + 1; q < r + g; q++) {
                        int s2 = slotL[ordL[q]];
                        if (s2 < bs) { bs = s2; bi = q; }
                    }
                    unsigned short w = ordL[bi];
                    ordL[bi] = ordL[r + t];
                    ordL[r + t] = w;
                    int d = batL[r + t];
                    batL[bs] = (unsigned short)d;
                    slotL[d] = (unsigned short)bs;
                }
                r += g;
            }
        }
    }
    __syncthreads();

    for (int r = tid; r < n; r += 256) {
        float s = svL[r];
        out[r] = s;
        out[n + r] = (float)ordL[r];
        out[2 * n + r] = (s > 0.05f) ? 1.f : 0.f;
    }
}

extern "C" void kernel_launch(void* const* d_in, const int* in_sizes, int n_in,
                              void* d_out, int out_size, void* d_ws, size_t ws_size,
                              hipStream_t stream) {
    const float* boxes  = (const float*)d_in[0];  // [N,4] f32
    const float* scores = (const float*)d_in[1];  // [N]   f32
    const int*   idxs   = (const int*)d_in[2];    // [N]   i32
    float* out = (float*)d_out;                   // scores | order | keep (f32)
    char* ws = (char*)d_ws;
    const int n = in_sizes[1];

    nms_class_kernel<<<NCLS, 256, 0, stream>>>(boxes, scores, idxs, ws, n);
    rank_finalize_kernel<<<RB, 256, 0, stream>>>(ws, out, n);
}